// Round 2
// baseline (5686.723 us; speedup 1.0000x reference)
//
#include <hip/hip_runtime.h>
#include <hip/hip_bf16.h>
#include <hip/hip_cooperative_groups.h>
#include <math.h>

namespace cg = cooperative_groups;

typedef __bf16 bf16_t;
typedef bf16_t bf16x8 __attribute__((ext_vector_type(8)));
typedef float f32x4 __attribute__((ext_vector_type(4)));

#define T_SEQ 128
#define NB 32
#define NV 32000
#define NE 512
#define NH 1024
#define G4 4096          // 4*NH
#define MROWS 4064       // 127*32
#define MPAD 4096

// ---------------- prep: casts, gather, zeroing ----------------
__global__ void k_prep(const int* __restrict__ idx, const float* __restrict__ emb,
                       const float* __restrict__ W_ih, const float* __restrict__ W_hh,
                       const float* __restrict__ b_ih, const float* __restrict__ b_hh,
                       const float* __restrict__ W_out, const float* __restrict__ h0,
                       bf16_t* __restrict__ W_ih_bf, bf16_t* __restrict__ W_hh_bf,
                       bf16_t* __restrict__ W_out_bf, bf16_t* __restrict__ x_bf,
                       bf16_t* __restrict__ h_all, bf16_t* __restrict__ h0_bf,
                       float* __restrict__ bc, float* __restrict__ rowS,
                       int* __restrict__ tgt) {
  const long nW_ih = 4096L * 512;
  const long nW_hh = 4096L * 1024;
  const long nW_out = 32000L * 1024;
  const long nX = 4096L * 512;
  const long nH0 = 32L * 1024;
  const long nHpad = 32L * 1024;
  const long NTOTAL = nW_ih + nW_hh + nW_out + nX + nH0 + nHpad + 3 * 4096L;
  long stride = (long)gridDim.x * blockDim.x;
  for (long i = (long)blockIdx.x * blockDim.x + threadIdx.x; i < NTOTAL; i += stride) {
    long j = i;
    if (j < nW_ih) { W_ih_bf[j] = (bf16_t)W_ih[j]; continue; }
    j -= nW_ih;
    if (j < nW_hh) { W_hh_bf[j] = (bf16_t)W_hh[j]; continue; }
    j -= nW_hh;
    if (j < nW_out) { W_out_bf[j] = (bf16_t)W_out[j]; continue; }
    j -= nW_out;
    if (j < nX) {
      long m = j >> 9; int e = (int)(j & 511);
      float x = 0.f;
      if (m < MROWS) { x = emb[(long)idx[m] * NE + e]; x = x > 0.f ? x : 0.f; }
      x_bf[j] = (bf16_t)x; continue;
    }
    j -= nX;
    if (j < nH0) { h0_bf[j] = (bf16_t)h0[j]; continue; }
    j -= nH0;
    if (j < nHpad) { h_all[4161536L + j] = (bf16_t)0.f; continue; }  // pad rows 4064..4095
    j -= nHpad;
    if (j < 4096) { bc[j] = b_ih[j] + b_hh[j]; continue; }
    j -= 4096;
    if (j < 4096) { rowS[j] = 0.f; continue; }
    j -= 4096;
    { tgt[j] = (j < MROWS) ? idx[j + NB] : 0; continue; }
  }
}

// ---------------- GEMM1: gates_x = x @ W_ih^T + (b_ih+b_hh), bf16 out ----------------
__global__ __launch_bounds__(256) void k_gemm1(const bf16_t* __restrict__ A,
                                               const bf16_t* __restrict__ B,
                                               const float* __restrict__ bc,
                                               bf16_t* __restrict__ C) {
  const int K = 512;
  int tid = threadIdx.x, wid = tid >> 6, lane = tid & 63;
  int wm = wid & 1, wn = wid >> 1;
  int quad = lane >> 4, l15 = lane & 15;
  int mBase = blockIdx.x * 64, nBase = blockIdx.y * 128;

  const bf16x8* pa0 = (const bf16x8*)(A + (long)(mBase + wm * 32 + l15) * K + quad * 8);
  const bf16x8* pa1 = (const bf16x8*)(A + (long)(mBase + wm * 32 + 16 + l15) * K + quad * 8);
  const bf16x8* pb[4];
#pragma unroll
  for (int j = 0; j < 4; ++j)
    pb[j] = (const bf16x8*)(B + (long)(nBase + wn * 64 + j * 16 + l15) * K + quad * 8);

  f32x4 acc[2][4];
#pragma unroll
  for (int mi = 0; mi < 2; ++mi)
#pragma unroll
    for (int ni = 0; ni < 4; ++ni) acc[mi][ni] = (f32x4){0.f, 0.f, 0.f, 0.f};

  for (int kk = 0; kk < K / 32; ++kk) {
    bf16x8 a0 = pa0[kk * 4], a1 = pa1[kk * 4];
    bf16x8 b0 = pb[0][kk * 4], b1 = pb[1][kk * 4], b2 = pb[2][kk * 4], b3 = pb[3][kk * 4];
    acc[0][0] = __builtin_amdgcn_mfma_f32_16x16x32_bf16(a0, b0, acc[0][0], 0, 0, 0);
    acc[0][1] = __builtin_amdgcn_mfma_f32_16x16x32_bf16(a0, b1, acc[0][1], 0, 0, 0);
    acc[0][2] = __builtin_amdgcn_mfma_f32_16x16x32_bf16(a0, b2, acc[0][2], 0, 0, 0);
    acc[0][3] = __builtin_amdgcn_mfma_f32_16x16x32_bf16(a0, b3, acc[0][3], 0, 0, 0);
    acc[1][0] = __builtin_amdgcn_mfma_f32_16x16x32_bf16(a1, b0, acc[1][0], 0, 0, 0);
    acc[1][1] = __builtin_amdgcn_mfma_f32_16x16x32_bf16(a1, b1, acc[1][1], 0, 0, 0);
    acc[1][2] = __builtin_amdgcn_mfma_f32_16x16x32_bf16(a1, b2, acc[1][2], 0, 0, 0);
    acc[1][3] = __builtin_amdgcn_mfma_f32_16x16x32_bf16(a1, b3, acc[1][3], 0, 0, 0);
  }
#pragma unroll
  for (int ni = 0; ni < 4; ++ni) {
    int col = nBase + wn * 64 + ni * 16 + l15;
    float bcv = bc[col];
#pragma unroll
    for (int mi = 0; mi < 2; ++mi)
#pragma unroll
      for (int r = 0; r < 4; ++r) {
        int row = mBase + wm * 32 + mi * 16 + quad * 4 + r;
        C[(long)row * G4 + col] = (bf16_t)(acc[mi][ni][r] + bcv);
      }
  }
}

// ---------------- cooperative LSTM recurrence v2 ----------------
// 256 blocks x 512 threads. Block = (unit-group of 8) x (batch half of 16).
// 8 waves/block: (cg in {0,1}: i/f cols vs g/o cols) x (kh in 0..3: K-quarter).
// W_hh fragments live in VGPRs for the whole kernel (fence can't evict them).
__global__ __launch_bounds__(512) void k_rec2(const bf16_t* __restrict__ gates_x,
                                              const bf16_t* __restrict__ W_hh_bf,
                                              const bf16_t* __restrict__ h0_bf,
                                              bf16_t* __restrict__ h_all,
                                              const float* __restrict__ c0) {
  cg::grid_group grid = cg::this_grid();
  __shared__ float red[2 * 16 * 16 * 4];  // [cg][b(16)][col(16)][kh(4)] f32

  int bid = blockIdx.x;
  int mi = bid & 1;              // batch half
  int gbase = (bid >> 1) * 8;    // first hidden unit owned by this block
  int tid = threadIdx.x, wid = tid >> 6, lane = tid & 63;
  int cg = wid & 1, kh = wid >> 1;
  int quad = lane >> 4, l15 = lane & 15;

  // B column l15 of this wave's 16x16 output tile -> W_hh gate row:
  // cg0: cols 0..7 = i rows, 8..15 = f rows; cg1: g / o rows.
  int wrow = (cg ? 2048 : 0) + ((l15 & 8) ? 1024 : 0) + gbase + (l15 & 7);
  const bf16x8* pw = (const bf16x8*)(W_hh_bf + (long)wrow * NH + kh * 256 + quad * 8);
  bf16x8 wfrag[8];
#pragma unroll
  for (int kk = 0; kk < 8; ++kk) wfrag[kk] = pw[kk * 4];  // resident in VGPRs

  // pointwise ownership: threads 0..127, b = tid>>3, u = tid&7
  int pb = tid >> 3, pu = tid & 7;
  int u_global = gbase + pu;
  int bglob = mi * 16 + pb;
  float cst = 0.f;
  if (tid < 128) cst = c0[(long)bglob * NH + u_global];

  for (int t = 0; t < T_SEQ - 1; ++t) {
    // prefetch gates_x contributions for pointwise (independent of h_prev)
    float gxi = 0.f, gxf = 0.f, gxg = 0.f, gxo = 0.f;
    if (tid < 128) {
      long m = (long)(t * NB + bglob) * G4;
      gxi = (float)gates_x[m + u_global];
      gxf = (float)gates_x[m + 1024 + u_global];
      gxg = (float)gates_x[m + 2048 + u_global];
      gxo = (float)gates_x[m + 3072 + u_global];
    }

    const bf16_t* hp = (t == 0) ? h0_bf : (h_all + (long)(t - 1) * NB * NH);
    const bf16x8* pa = (const bf16x8*)(hp + (long)(mi * 16 + l15) * NH + kh * 256 + quad * 8);
    f32x4 acc = (f32x4){0.f, 0.f, 0.f, 0.f};
#pragma unroll
    for (int kk = 0; kk < 8; ++kk) {
      bf16x8 a = pa[kk * 4];
      acc = __builtin_amdgcn_mfma_f32_16x16x32_bf16(a, wfrag[kk], acc, 0, 0, 0);
    }
#pragma unroll
    for (int r = 0; r < 4; ++r) {
      int b = quad * 4 + r;
      red[(((cg << 4) + b) << 6) + (l15 << 2) + kh] = acc[r];
    }
    __syncthreads();

    if (tid < 128) {
      const float4* rp = (const float4*)red;  // float4 unit idx = (cg*16+b)*16 + col
      float4 vi = rp[((0 + pb) << 4) + pu];
      float4 vf = rp[((0 + pb) << 4) + 8 + pu];
      float4 vg = rp[((16 + pb) << 4) + pu];
      float4 vo = rp[((16 + pb) << 4) + 8 + pu];
      float iv = vi.x + vi.y + vi.z + vi.w + gxi;
      float fv = vf.x + vf.y + vf.z + vf.w + gxf;
      float gv = vg.x + vg.y + vg.z + vg.w + gxg;
      float ov = vo.x + vo.y + vo.z + vo.w + gxo;
      float si = 1.f / (1.f + __expf(-iv));
      float sf = 1.f / (1.f + __expf(-fv));
      float so = 1.f / (1.f + __expf(-ov));
      float tg = 1.f - 2.f / (__expf(2.f * gv) + 1.f);
      cst = sf * cst + si * tg;
      float th = 1.f - 2.f / (__expf(2.f * cst) + 1.f);
      h_all[(long)(t * NB + bglob) * NH + u_global] = (bf16_t)(so * th);
    }
    grid.sync();
  }
}

// ---------------- GEMM2: logits + exp-rowsum epilogue ----------------
__global__ __launch_bounds__(256) void k_gemm2(const bf16_t* __restrict__ A,
                                               const bf16_t* __restrict__ B,
                                               const float* __restrict__ b_out,
                                               float* __restrict__ rowS) {
  const int K = 1024;
  int tid = threadIdx.x, wid = tid >> 6, lane = tid & 63;
  int wm = wid & 1, wn = wid >> 1;
  int quad = lane >> 4, l15 = lane & 15;
  int mBase = blockIdx.x * 64, nBase = blockIdx.y * 128;

  const bf16x8* pa0 = (const bf16x8*)(A + (long)(mBase + wm * 32 + l15) * K + quad * 8);
  const bf16x8* pa1 = (const bf16x8*)(A + (long)(mBase + wm * 32 + 16 + l15) * K + quad * 8);
  const bf16x8* pb[4];
#pragma unroll
  for (int j = 0; j < 4; ++j)
    pb[j] = (const bf16x8*)(B + (long)(nBase + wn * 64 + j * 16 + l15) * K + quad * 8);

  f32x4 acc[2][4];
#pragma unroll
  for (int mi = 0; mi < 2; ++mi)
#pragma unroll
    for (int ni = 0; ni < 4; ++ni) acc[mi][ni] = (f32x4){0.f, 0.f, 0.f, 0.f};

  for (int kk = 0; kk < K / 32; ++kk) {
    bf16x8 a0 = pa0[kk * 4], a1 = pa1[kk * 4];
    bf16x8 b0 = pb[0][kk * 4], b1 = pb[1][kk * 4], b2 = pb[2][kk * 4], b3 = pb[3][kk * 4];
    acc[0][0] = __builtin_amdgcn_mfma_f32_16x16x32_bf16(a0, b0, acc[0][0], 0, 0, 0);
    acc[0][1] = __builtin_amdgcn_mfma_f32_16x16x32_bf16(a0, b1, acc[0][1], 0, 0, 0);
    acc[0][2] = __builtin_amdgcn_mfma_f32_16x16x32_bf16(a0, b2, acc[0][2], 0, 0, 0);
    acc[0][3] = __builtin_amdgcn_mfma_f32_16x16x32_bf16(a0, b3, acc[0][3], 0, 0, 0);
    acc[1][0] = __builtin_amdgcn_mfma_f32_16x16x32_bf16(a1, b0, acc[1][0], 0, 0, 0);
    acc[1][1] = __builtin_amdgcn_mfma_f32_16x16x32_bf16(a1, b1, acc[1][1], 0, 0, 0);
    acc[1][2] = __builtin_amdgcn_mfma_f32_16x16x32_bf16(a1, b2, acc[1][2], 0, 0, 0);
    acc[1][3] = __builtin_amdgcn_mfma_f32_16x16x32_bf16(a1, b3, acc[1][3], 0, 0, 0);
  }

#pragma unroll
  for (int mi = 0; mi < 2; ++mi) {
    float rs[4] = {0.f, 0.f, 0.f, 0.f};
#pragma unroll
    for (int ni = 0; ni < 4; ++ni) {
      int col = nBase + wn * 64 + ni * 16 + l15;
      float bb = b_out[col];
#pragma unroll
      for (int r = 0; r < 4; ++r) rs[r] += __expf(acc[mi][ni][r] + bb);
    }
#pragma unroll
    for (int r = 0; r < 4; ++r) {
#pragma unroll
      for (int s = 1; s < 16; s <<= 1) rs[r] += __shfl_xor(rs[r], s);
      if (l15 == 0) {
        int row = mBase + wm * 32 + mi * 16 + quad * 4 + r;
        if (row < MROWS) atomicAdd(&rowS[row], rs[r]);
      }
    }
  }
}

// ---------------- target logits ----------------
__global__ __launch_bounds__(256) void k_tgt(const bf16_t* __restrict__ h_all,
                                             const bf16_t* __restrict__ W_out_bf,
                                             const float* __restrict__ b_out,
                                             const int* __restrict__ tgt,
                                             float* __restrict__ tgt_logit) {
  int gw = (int)((blockIdx.x * blockDim.x + threadIdx.x) >> 6);
  int lane = threadIdx.x & 63;
  if (gw >= MROWS) return;
  int v = tgt[gw];
  const bf16x8* ph = (const bf16x8*)(h_all + (long)gw * NH + lane * 16);
  const bf16x8* pw = (const bf16x8*)(W_out_bf + (long)v * NH + lane * 16);
  float acc = 0.f;
#pragma unroll
  for (int j = 0; j < 2; ++j) {
    bf16x8 h8 = ph[j], w8 = pw[j];
#pragma unroll
    for (int q = 0; q < 8; ++q) acc += (float)h8[q] * (float)w8[q];
  }
#pragma unroll
  for (int s = 1; s < 64; s <<= 1) acc += __shfl_xor(acc, s);
  if (lane == 0) tgt_logit[gw] = acc + b_out[v];
}

// ---------------- final loss reduction ----------------
__global__ __launch_bounds__(256) void k_loss(const float* __restrict__ rowS,
                                              const float* __restrict__ tl,
                                              const int* __restrict__ tgt,
                                              float* __restrict__ out) {
  __shared__ float sm[256];
  float s = 0.f;
  for (int i = threadIdx.x; i < MROWS; i += 256)
    if (tgt[i] != 0) s += logf(rowS[i]) - tl[i];
  sm[threadIdx.x] = s;
  __syncthreads();
  for (int off = 128; off > 0; off >>= 1) {
    if (threadIdx.x < off) sm[threadIdx.x] += sm[threadIdx.x + off];
    __syncthreads();
  }
  if (threadIdx.x == 0) out[0] = sm[0];
}

extern "C" void kernel_launch(void* const* d_in, const int* in_sizes, int n_in,
                              void* d_out, int out_size, void* d_ws, size_t ws_size,
                              hipStream_t stream) {
  const int* idx = (const int*)d_in[0];
  const float* emb = (const float*)d_in[1];
  const float* W_ih = (const float*)d_in[2];
  const float* W_hh = (const float*)d_in[3];
  const float* b_ih = (const float*)d_in[4];
  const float* b_hh = (const float*)d_in[5];
  const float* W_out = (const float*)d_in[6];
  const float* b_out = (const float*)d_in[7];
  const float* h0 = (const float*)d_in[8];
  const float* c0 = (const float*)d_in[9];

  char* ws = (char*)d_ws;
  bf16_t* W_ih_bf = (bf16_t*)ws;            ws += 4096L * 512 * 2;
  bf16_t* W_hh_bf = (bf16_t*)ws;            ws += 4096L * 1024 * 2;
  bf16_t* W_out_bf = (bf16_t*)ws;           ws += 32000L * 1024 * 2;
  bf16_t* x_bf = (bf16_t*)ws;               ws += 4096L * 512 * 2;
  bf16_t* gates_x = (bf16_t*)ws;            ws += 4096L * 4096 * 2;
  bf16_t* h_all = (bf16_t*)ws;              ws += 4096L * 1024 * 2;
  bf16_t* h0_bf = (bf16_t*)ws;              ws += 32L * 1024 * 2;
  float* bc = (float*)ws;                   ws += 4096L * 4;
  float* rowS = (float*)ws;                 ws += 4096L * 4;
  float* tgt_logit = (float*)ws;            ws += 4096L * 4;
  int* tgt = (int*)ws;                      ws += 4096L * 4;

  k_prep<<<4096, 256, 0, stream>>>(idx, emb, W_ih, W_hh, b_ih, b_hh, W_out, h0,
                                   W_ih_bf, W_hh_bf, W_out_bf, x_bf, h_all, h0_bf,
                                   bc, rowS, tgt);

  k_gemm1<<<dim3(64, 32), 256, 0, stream>>>(x_bf, W_ih_bf, bc, gates_x);

  {
    void* args[] = {(void*)&gates_x, (void*)&W_hh_bf, (void*)&h0_bf, (void*)&h_all, (void*)&c0};
    hipLaunchCooperativeKernel((void*)k_rec2, dim3(256), dim3(512), args, 0, stream);
  }

  k_gemm2<<<dim3(64, 250), 256, 0, stream>>>(h_all, W_out_bf, b_out, rowS);

  k_tgt<<<1016, 256, 0, stream>>>(h_all, W_out_bf, b_out, tgt, tgt_logit);

  k_loss<<<1, 256, 0, stream>>>(rowS, tgt_logit, tgt, (float*)d_out);
}

// Round 3
// 3054.568 us; speedup vs baseline: 1.8617x; 1.8617x over previous
//
#include <hip/hip_runtime.h>
#include <hip/hip_bf16.h>
#include <hip/hip_cooperative_groups.h>
#include <math.h>

namespace cg = cooperative_groups;

typedef __bf16 bf16_t;
typedef bf16_t bf16x8 __attribute__((ext_vector_type(8)));
typedef float f32x4 __attribute__((ext_vector_type(4)));

#define T_SEQ 128
#define NB 32
#define NV 32000
#define NE 512
#define NH 1024
#define G4 4096          // 4*NH
#define MROWS 4064       // 127*32
#define MPAD 4096

#define NBLK 256
#define NGRP 16

// ---------------- prep: casts, gather, zeroing ----------------
__global__ void k_prep(const int* __restrict__ idx, const float* __restrict__ emb,
                       const float* __restrict__ W_ih, const float* __restrict__ W_hh,
                       const float* __restrict__ b_ih, const float* __restrict__ b_hh,
                       const float* __restrict__ W_out, const float* __restrict__ h0,
                       bf16_t* __restrict__ W_ih_bf, bf16_t* __restrict__ W_hh_bf,
                       bf16_t* __restrict__ W_out_bf, bf16_t* __restrict__ x_bf,
                       bf16_t* __restrict__ h_all, bf16_t* __restrict__ h0_bf,
                       float* __restrict__ bc, float* __restrict__ rowS,
                       int* __restrict__ tgt, unsigned* __restrict__ bar) {
  const long nW_ih = 4096L * 512;
  const long nW_hh = 4096L * 1024;
  const long nW_out = 32000L * 1024;
  const long nX = 4096L * 512;
  const long nH0 = 32L * 1024;
  const long nHpad = 32L * 1024;
  const long NTOTAL = nW_ih + nW_hh + nW_out + nX + nH0 + nHpad + 3 * 4096L + 1024;
  long stride = (long)gridDim.x * blockDim.x;
  for (long i = (long)blockIdx.x * blockDim.x + threadIdx.x; i < NTOTAL; i += stride) {
    long j = i;
    if (j < nW_ih) { W_ih_bf[j] = (bf16_t)W_ih[j]; continue; }
    j -= nW_ih;
    if (j < nW_hh) { W_hh_bf[j] = (bf16_t)W_hh[j]; continue; }
    j -= nW_hh;
    if (j < nW_out) { W_out_bf[j] = (bf16_t)W_out[j]; continue; }
    j -= nW_out;
    if (j < nX) {
      long m = j >> 9; int e = (int)(j & 511);
      float x = 0.f;
      if (m < MROWS) { x = emb[(long)idx[m] * NE + e]; x = x > 0.f ? x : 0.f; }
      x_bf[j] = (bf16_t)x; continue;
    }
    j -= nX;
    if (j < nH0) { h0_bf[j] = (bf16_t)h0[j]; continue; }
    j -= nH0;
    if (j < nHpad) { h_all[4161536L + j] = (bf16_t)0.f; continue; }  // pad rows 4064..4095
    j -= nHpad;
    if (j < 4096) { bc[j] = b_ih[j] + b_hh[j]; continue; }
    j -= 4096;
    if (j < 4096) { rowS[j] = 0.f; continue; }
    j -= 4096;
    if (j < 4096) { tgt[j] = (j < MROWS) ? idx[j + NB] : 0; continue; }
    j -= 4096;
    { bar[j] = 0u; continue; }
  }
}

// ---------------- GEMM1: gates_x = x @ W_ih^T + (b_ih+b_hh), bf16 out ----------------
__global__ __launch_bounds__(256) void k_gemm1(const bf16_t* __restrict__ A,
                                               const bf16_t* __restrict__ B,
                                               const float* __restrict__ bc,
                                               bf16_t* __restrict__ C) {
  const int K = 512;
  int tid = threadIdx.x, wid = tid >> 6, lane = tid & 63;
  int wm = wid & 1, wn = wid >> 1;
  int quad = lane >> 4, l15 = lane & 15;
  int mBase = blockIdx.x * 64, nBase = blockIdx.y * 128;

  const bf16x8* pa0 = (const bf16x8*)(A + (long)(mBase + wm * 32 + l15) * K + quad * 8);
  const bf16x8* pa1 = (const bf16x8*)(A + (long)(mBase + wm * 32 + 16 + l15) * K + quad * 8);
  const bf16x8* pb[4];
#pragma unroll
  for (int j = 0; j < 4; ++j)
    pb[j] = (const bf16x8*)(B + (long)(nBase + wn * 64 + j * 16 + l15) * K + quad * 8);

  f32x4 acc[2][4];
#pragma unroll
  for (int mi = 0; mi < 2; ++mi)
#pragma unroll
    for (int ni = 0; ni < 4; ++ni) acc[mi][ni] = (f32x4){0.f, 0.f, 0.f, 0.f};

  for (int kk = 0; kk < K / 32; ++kk) {
    bf16x8 a0 = pa0[kk * 4], a1 = pa1[kk * 4];
    bf16x8 b0 = pb[0][kk * 4], b1 = pb[1][kk * 4], b2 = pb[2][kk * 4], b3 = pb[3][kk * 4];
    acc[0][0] = __builtin_amdgcn_mfma_f32_16x16x32_bf16(a0, b0, acc[0][0], 0, 0, 0);
    acc[0][1] = __builtin_amdgcn_mfma_f32_16x16x32_bf16(a0, b1, acc[0][1], 0, 0, 0);
    acc[0][2] = __builtin_amdgcn_mfma_f32_16x16x32_bf16(a0, b2, acc[0][2], 0, 0, 0);
    acc[0][3] = __builtin_amdgcn_mfma_f32_16x16x32_bf16(a0, b3, acc[0][3], 0, 0, 0);
    acc[1][0] = __builtin_amdgcn_mfma_f32_16x16x32_bf16(a1, b0, acc[1][0], 0, 0, 0);
    acc[1][1] = __builtin_amdgcn_mfma_f32_16x16x32_bf16(a1, b1, acc[1][1], 0, 0, 0);
    acc[1][2] = __builtin_amdgcn_mfma_f32_16x16x32_bf16(a1, b2, acc[1][2], 0, 0, 0);
    acc[1][3] = __builtin_amdgcn_mfma_f32_16x16x32_bf16(a1, b3, acc[1][3], 0, 0, 0);
  }
#pragma unroll
  for (int ni = 0; ni < 4; ++ni) {
    int col = nBase + wn * 64 + ni * 16 + l15;
    float bcv = bc[col];
#pragma unroll
    for (int mi = 0; mi < 2; ++mi)
#pragma unroll
      for (int r = 0; r < 4; ++r) {
        int row = mBase + wm * 32 + mi * 16 + quad * 4 + r;
        C[(long)row * G4 + col] = (bf16_t)(acc[mi][ni][r] + bcv);
      }
  }
}

// ---------------- hand-rolled two-level grid barrier ----------------
// bar layout (unsigned): [g*32] for g in 0..15 = group counters (128B apart)
//                        [512] = root counter, [544] = generation word
__device__ __forceinline__ void gbar(unsigned* bar, unsigned target) {
  __syncthreads();
  if (threadIdx.x == 0) {
    __builtin_amdgcn_fence(__ATOMIC_RELEASE, "agent");   // flush h stores to LLC
    unsigned grp = blockIdx.x & (NGRP - 1);
    unsigned o = __hip_atomic_fetch_add(&bar[grp * 32], 1u, __ATOMIC_RELAXED,
                                        __HIP_MEMORY_SCOPE_AGENT);
    if (o == (NBLK / NGRP) - 1) {
      __hip_atomic_store(&bar[grp * 32], 0u, __ATOMIC_RELAXED, __HIP_MEMORY_SCOPE_AGENT);
      unsigned r = __hip_atomic_fetch_add(&bar[512], 1u, __ATOMIC_RELAXED,
                                          __HIP_MEMORY_SCOPE_AGENT);
      if (r == NGRP - 1) {
        __hip_atomic_store(&bar[512], 0u, __ATOMIC_RELAXED, __HIP_MEMORY_SCOPE_AGENT);
        __hip_atomic_store(&bar[544], target, __ATOMIC_RELAXED, __HIP_MEMORY_SCOPE_AGENT);
      }
    }
    while (__hip_atomic_load(&bar[544], __ATOMIC_RELAXED, __HIP_MEMORY_SCOPE_AGENT) != target) {
      __builtin_amdgcn_s_sleep(1);
    }
    __builtin_amdgcn_fence(__ATOMIC_ACQUIRE, "agent");   // invalidate stale h
  }
  __syncthreads();
}

// ---------------- cooperative LSTM recurrence v3 (custom barrier) ----------------
// 256 blocks x 512 threads. Block = (unit-group of 8) x (batch half of 16).
// W_hh fragments live in VGPRs for the whole kernel.
__global__ __launch_bounds__(512) void k_rec3(const bf16_t* __restrict__ gates_x,
                                              const bf16_t* __restrict__ W_hh_bf,
                                              const bf16_t* __restrict__ h0_bf,
                                              bf16_t* __restrict__ h_all,
                                              const float* __restrict__ c0,
                                              unsigned* __restrict__ bar) {
  __shared__ float red[2 * 16 * 16 * 4];  // [cg][b(16)][col(16)][kh(4)] f32

  int bid = blockIdx.x;
  int mi = bid & 1;              // batch half
  int gbase = (bid >> 1) * 8;    // first hidden unit owned by this block
  int tid = threadIdx.x, wid = tid >> 6, lane = tid & 63;
  int cg = wid & 1, kh = wid >> 1;
  int quad = lane >> 4, l15 = lane & 15;

  int wrow = (cg ? 2048 : 0) + ((l15 & 8) ? 1024 : 0) + gbase + (l15 & 7);
  const bf16x8* pw = (const bf16x8*)(W_hh_bf + (long)wrow * NH + kh * 256 + quad * 8);
  bf16x8 wfrag[8];
#pragma unroll
  for (int kk = 0; kk < 8; ++kk) wfrag[kk] = pw[kk * 4];  // resident in VGPRs

  int pb = tid >> 3, pu = tid & 7;
  int u_global = gbase + pu;
  int bglob = mi * 16 + pb;
  float cst = 0.f;
  if (tid < 128) cst = c0[(long)bglob * NH + u_global];

  for (int t = 0; t < T_SEQ - 1; ++t) {
    float gxi = 0.f, gxf = 0.f, gxg = 0.f, gxo = 0.f;
    if (tid < 128) {
      long m = (long)(t * NB + bglob) * G4;
      gxi = (float)gates_x[m + u_global];
      gxf = (float)gates_x[m + 1024 + u_global];
      gxg = (float)gates_x[m + 2048 + u_global];
      gxo = (float)gates_x[m + 3072 + u_global];
    }

    const bf16_t* hp = (t == 0) ? h0_bf : (h_all + (long)(t - 1) * NB * NH);
    const bf16x8* pa = (const bf16x8*)(hp + (long)(mi * 16 + l15) * NH + kh * 256 + quad * 8);
    f32x4 acc = (f32x4){0.f, 0.f, 0.f, 0.f};
#pragma unroll
    for (int kk = 0; kk < 8; ++kk) {
      bf16x8 a = pa[kk * 4];
      acc = __builtin_amdgcn_mfma_f32_16x16x32_bf16(a, wfrag[kk], acc, 0, 0, 0);
    }
#pragma unroll
    for (int r = 0; r < 4; ++r) {
      int b = quad * 4 + r;
      red[(((cg << 4) + b) << 6) + (l15 << 2) + kh] = acc[r];
    }
    __syncthreads();

    if (tid < 128) {
      const float4* rp = (const float4*)red;
      float4 vi = rp[((0 + pb) << 4) + pu];
      float4 vf = rp[((0 + pb) << 4) + 8 + pu];
      float4 vg = rp[((16 + pb) << 4) + pu];
      float4 vo = rp[((16 + pb) << 4) + 8 + pu];
      float iv = vi.x + vi.y + vi.z + vi.w + gxi;
      float fv = vf.x + vf.y + vf.z + vf.w + gxf;
      float gv = vg.x + vg.y + vg.z + vg.w + gxg;
      float ov = vo.x + vo.y + vo.z + vo.w + gxo;
      float si = 1.f / (1.f + __expf(-iv));
      float sf = 1.f / (1.f + __expf(-fv));
      float so = 1.f / (1.f + __expf(-ov));
      float tg = 1.f - 2.f / (__expf(2.f * gv) + 1.f);
      cst = sf * cst + si * tg;
      float th = 1.f - 2.f / (__expf(2.f * cst) + 1.f);
      h_all[(long)(t * NB + bglob) * NH + u_global] = (bf16_t)(so * th);
    }
    gbar(bar, (unsigned)(t + 1));
  }
}

// ---------------- GEMM2: logits + exp-rowsum epilogue ----------------
__global__ __launch_bounds__(256) void k_gemm2(const bf16_t* __restrict__ A,
                                               const bf16_t* __restrict__ B,
                                               const float* __restrict__ b_out,
                                               float* __restrict__ rowS) {
  const int K = 1024;
  int tid = threadIdx.x, wid = tid >> 6, lane = tid & 63;
  int wm = wid & 1, wn = wid >> 1;
  int quad = lane >> 4, l15 = lane & 15;
  int mBase = blockIdx.x * 64, nBase = blockIdx.y * 128;

  const bf16x8* pa0 = (const bf16x8*)(A + (long)(mBase + wm * 32 + l15) * K + quad * 8);
  const bf16x8* pa1 = (const bf16x8*)(A + (long)(mBase + wm * 32 + 16 + l15) * K + quad * 8);
  const bf16x8* pb[4];
#pragma unroll
  for (int j = 0; j < 4; ++j)
    pb[j] = (const bf16x8*)(B + (long)(nBase + wn * 64 + j * 16 + l15) * K + quad * 8);

  f32x4 acc[2][4];
#pragma unroll
  for (int mi = 0; mi < 2; ++mi)
#pragma unroll
    for (int ni = 0; ni < 4; ++ni) acc[mi][ni] = (f32x4){0.f, 0.f, 0.f, 0.f};

  for (int kk = 0; kk < K / 32; ++kk) {
    bf16x8 a0 = pa0[kk * 4], a1 = pa1[kk * 4];
    bf16x8 b0 = pb[0][kk * 4], b1 = pb[1][kk * 4], b2 = pb[2][kk * 4], b3 = pb[3][kk * 4];
    acc[0][0] = __builtin_amdgcn_mfma_f32_16x16x32_bf16(a0, b0, acc[0][0], 0, 0, 0);
    acc[0][1] = __builtin_amdgcn_mfma_f32_16x16x32_bf16(a0, b1, acc[0][1], 0, 0, 0);
    acc[0][2] = __builtin_amdgcn_mfma_f32_16x16x32_bf16(a0, b2, acc[0][2], 0, 0, 0);
    acc[0][3] = __builtin_amdgcn_mfma_f32_16x16x32_bf16(a0, b3, acc[0][3], 0, 0, 0);
    acc[1][0] = __builtin_amdgcn_mfma_f32_16x16x32_bf16(a1, b0, acc[1][0], 0, 0, 0);
    acc[1][1] = __builtin_amdgcn_mfma_f32_16x16x32_bf16(a1, b1, acc[1][1], 0, 0, 0);
    acc[1][2] = __builtin_amdgcn_mfma_f32_16x16x32_bf16(a1, b2, acc[1][2], 0, 0, 0);
    acc[1][3] = __builtin_amdgcn_mfma_f32_16x16x32_bf16(a1, b3, acc[1][3], 0, 0, 0);
  }

#pragma unroll
  for (int mi = 0; mi < 2; ++mi) {
    float rs[4] = {0.f, 0.f, 0.f, 0.f};
#pragma unroll
    for (int ni = 0; ni < 4; ++ni) {
      int col = nBase + wn * 64 + ni * 16 + l15;
      float bb = b_out[col];
#pragma unroll
      for (int r = 0; r < 4; ++r) rs[r] += __expf(acc[mi][ni][r] + bb);
    }
#pragma unroll
    for (int r = 0; r < 4; ++r) {
#pragma unroll
      for (int s = 1; s < 16; s <<= 1) rs[r] += __shfl_xor(rs[r], s);
      if (l15 == 0) {
        int row = mBase + wm * 32 + mi * 16 + quad * 4 + r;
        if (row < MROWS) atomicAdd(&rowS[row], rs[r]);
      }
    }
  }
}

// ---------------- target logits ----------------
__global__ __launch_bounds__(256) void k_tgt(const bf16_t* __restrict__ h_all,
                                             const bf16_t* __restrict__ W_out_bf,
                                             const float* __restrict__ b_out,
                                             const int* __restrict__ tgt,
                                             float* __restrict__ tgt_logit) {
  int gw = (int)((blockIdx.x * blockDim.x + threadIdx.x) >> 6);
  int lane = threadIdx.x & 63;
  if (gw >= MROWS) return;
  int v = tgt[gw];
  const bf16x8* ph = (const bf16x8*)(h_all + (long)gw * NH + lane * 16);
  const bf16x8* pw = (const bf16x8*)(W_out_bf + (long)v * NH + lane * 16);
  float acc = 0.f;
#pragma unroll
  for (int j = 0; j < 2; ++j) {
    bf16x8 h8 = ph[j], w8 = pw[j];
#pragma unroll
    for (int q = 0; q < 8; ++q) acc += (float)h8[q] * (float)w8[q];
  }
#pragma unroll
  for (int s = 1; s < 64; s <<= 1) acc += __shfl_xor(acc, s);
  if (lane == 0) tgt_logit[gw] = acc + b_out[v];
}

// ---------------- final loss reduction ----------------
__global__ __launch_bounds__(256) void k_loss(const float* __restrict__ rowS,
                                              const float* __restrict__ tl,
                                              const int* __restrict__ tgt,
                                              float* __restrict__ out) {
  __shared__ float sm[256];
  float s = 0.f;
  for (int i = threadIdx.x; i < MROWS; i += 256)
    if (tgt[i] != 0) s += logf(rowS[i]) - tl[i];
  sm[threadIdx.x] = s;
  __syncthreads();
  for (int off = 128; off > 0; off >>= 1) {
    if (threadIdx.x < off) sm[threadIdx.x] += sm[threadIdx.x + off];
    __syncthreads();
  }
  if (threadIdx.x == 0) out[0] = sm[0];
}

extern "C" void kernel_launch(void* const* d_in, const int* in_sizes, int n_in,
                              void* d_out, int out_size, void* d_ws, size_t ws_size,
                              hipStream_t stream) {
  const int* idx = (const int*)d_in[0];
  const float* emb = (const float*)d_in[1];
  const float* W_ih = (const float*)d_in[2];
  const float* W_hh = (const float*)d_in[3];
  const float* b_ih = (const float*)d_in[4];
  const float* b_hh = (const float*)d_in[5];
  const float* W_out = (const float*)d_in[6];
  const float* b_out = (const float*)d_in[7];
  const float* h0 = (const float*)d_in[8];
  const float* c0 = (const float*)d_in[9];

  char* ws = (char*)d_ws;
  bf16_t* W_ih_bf = (bf16_t*)ws;            ws += 4096L * 512 * 2;
  bf16_t* W_hh_bf = (bf16_t*)ws;            ws += 4096L * 1024 * 2;
  bf16_t* W_out_bf = (bf16_t*)ws;           ws += 32000L * 1024 * 2;
  bf16_t* x_bf = (bf16_t*)ws;               ws += 4096L * 512 * 2;
  bf16_t* gates_x = (bf16_t*)ws;            ws += 4096L * 4096 * 2;
  bf16_t* h_all = (bf16_t*)ws;              ws += 4096L * 1024 * 2;
  bf16_t* h0_bf = (bf16_t*)ws;              ws += 32L * 1024 * 2;
  float* bc = (float*)ws;                   ws += 4096L * 4;
  float* rowS = (float*)ws;                 ws += 4096L * 4;
  float* tgt_logit = (float*)ws;            ws += 4096L * 4;
  int* tgt = (int*)ws;                      ws += 4096L * 4;
  unsigned* bar = (unsigned*)ws;            ws += 1024L * 4;

  k_prep<<<4096, 256, 0, stream>>>(idx, emb, W_ih, W_hh, b_ih, b_hh, W_out, h0,
                                   W_ih_bf, W_hh_bf, W_out_bf, x_bf, h_all, h0_bf,
                                   bc, rowS, tgt, bar);

  k_gemm1<<<dim3(64, 32), 256, 0, stream>>>(x_bf, W_ih_bf, bc, gates_x);

  {
    void* args[] = {(void*)&gates_x, (void*)&W_hh_bf, (void*)&h0_bf, (void*)&h_all,
                    (void*)&c0, (void*)&bar};
    hipLaunchCooperativeKernel((void*)k_rec3, dim3(NBLK), dim3(512), args, 0, stream);
  }

  k_gemm2<<<dim3(64, 250), 256, 0, stream>>>(h_all, W_out_bf, b_out, rowS);

  k_tgt<<<1016, 256, 0, stream>>>(h_all, W_out_bf, b_out, tgt, tgt_logit);

  k_loss<<<1, 256, 0, stream>>>(rowS, tgt_logit, tgt, (float*)d_out);
}

// Round 4
// 2041.931 us; speedup vs baseline: 2.7850x; 1.4959x over previous
//
#include <hip/hip_runtime.h>
#include <hip/hip_bf16.h>
#include <hip/hip_cooperative_groups.h>
#include <math.h>

namespace cg = cooperative_groups;

typedef __bf16 bf16_t;
typedef bf16_t bf16x8 __attribute__((ext_vector_type(8)));
typedef float f32x4 __attribute__((ext_vector_type(4)));

#define T_SEQ 128
#define NB 32
#define NV 32000
#define NE 512
#define NH 1024
#define G4 4096          // 4*NH
#define MROWS 4064       // 127*32
#define MPAD 4096

#define NBLK 256
#define NGRP 16

// async global->LDS, 16B per lane, wave-uniform LDS base
__device__ __forceinline__ void g2lds16(const bf16_t* g, bf16_t* l) {
  __builtin_amdgcn_global_load_lds((const __attribute__((address_space(1))) void*)g,
                                   (__attribute__((address_space(3))) void*)l, 16, 0, 0);
}

// ---------------- prep: casts, gather, zeroing ----------------
__global__ void k_prep(const int* __restrict__ idx, const float* __restrict__ emb,
                       const float* __restrict__ W_ih, const float* __restrict__ W_hh,
                       const float* __restrict__ b_ih, const float* __restrict__ b_hh,
                       const float* __restrict__ W_out, const float* __restrict__ h0,
                       bf16_t* __restrict__ W_ih_bf, bf16_t* __restrict__ W_hh_bf,
                       bf16_t* __restrict__ W_out_bf, bf16_t* __restrict__ x_bf,
                       bf16_t* __restrict__ h_all, bf16_t* __restrict__ h0_bf,
                       float* __restrict__ bc, float* __restrict__ rowS,
                       int* __restrict__ tgt, unsigned* __restrict__ bar) {
  const long nW_ih = 4096L * 512;
  const long nW_hh = 4096L * 1024;
  const long nW_out = 32000L * 1024;
  const long nX = 4096L * 512;
  const long nH0 = 32L * 1024;
  const long nHpad = 32L * 1024;
  const long NTOTAL = nW_ih + nW_hh + nW_out + nX + nH0 + nHpad + 3 * 4096L + 1024;
  long stride = (long)gridDim.x * blockDim.x;
  for (long i = (long)blockIdx.x * blockDim.x + threadIdx.x; i < NTOTAL; i += stride) {
    long j = i;
    if (j < nW_ih) { W_ih_bf[j] = (bf16_t)W_ih[j]; continue; }
    j -= nW_ih;
    if (j < nW_hh) { W_hh_bf[j] = (bf16_t)W_hh[j]; continue; }
    j -= nW_hh;
    if (j < nW_out) { W_out_bf[j] = (bf16_t)W_out[j]; continue; }
    j -= nW_out;
    if (j < nX) {
      long m = j >> 9; int e = (int)(j & 511);
      float x = 0.f;
      if (m < MROWS) { x = emb[(long)idx[m] * NE + e]; x = x > 0.f ? x : 0.f; }
      x_bf[j] = (bf16_t)x; continue;
    }
    j -= nX;
    if (j < nH0) { h0_bf[j] = (bf16_t)h0[j]; continue; }
    j -= nH0;
    if (j < nHpad) { h_all[4161536L + j] = (bf16_t)0.f; continue; }  // pad rows 4064..4095
    j -= nHpad;
    if (j < 4096) { bc[j] = b_ih[j] + b_hh[j]; continue; }
    j -= 4096;
    if (j < 4096) { rowS[j] = 0.f; continue; }
    j -= 4096;
    if (j < 4096) { tgt[j] = (j < MROWS) ? idx[j + NB] : 0; continue; }
    j -= 4096;
    { bar[j] = 0u; continue; }
  }
}

// ---------------- GEMM1: gates_x = x @ W_ih^T + (b_ih+b_hh), bf16 out ----------------
__global__ __launch_bounds__(256) void k_gemm1(const bf16_t* __restrict__ A,
                                               const bf16_t* __restrict__ B,
                                               const float* __restrict__ bc,
                                               bf16_t* __restrict__ C) {
  const int K = 512;
  int tid = threadIdx.x, wid = tid >> 6, lane = tid & 63;
  int wm = wid & 1, wn = wid >> 1;
  int quad = lane >> 4, l15 = lane & 15;
  int mBase = blockIdx.x * 64, nBase = blockIdx.y * 128;

  const bf16x8* pa0 = (const bf16x8*)(A + (long)(mBase + wm * 32 + l15) * K + quad * 8);
  const bf16x8* pa1 = (const bf16x8*)(A + (long)(mBase + wm * 32 + 16 + l15) * K + quad * 8);
  const bf16x8* pb[4];
#pragma unroll
  for (int j = 0; j < 4; ++j)
    pb[j] = (const bf16x8*)(B + (long)(nBase + wn * 64 + j * 16 + l15) * K + quad * 8);

  f32x4 acc[2][4];
#pragma unroll
  for (int mi = 0; mi < 2; ++mi)
#pragma unroll
    for (int ni = 0; ni < 4; ++ni) acc[mi][ni] = (f32x4){0.f, 0.f, 0.f, 0.f};

  for (int kk = 0; kk < K / 32; ++kk) {
    bf16x8 a0 = pa0[kk * 4], a1 = pa1[kk * 4];
    bf16x8 b0 = pb[0][kk * 4], b1 = pb[1][kk * 4], b2 = pb[2][kk * 4], b3 = pb[3][kk * 4];
    acc[0][0] = __builtin_amdgcn_mfma_f32_16x16x32_bf16(a0, b0, acc[0][0], 0, 0, 0);
    acc[0][1] = __builtin_amdgcn_mfma_f32_16x16x32_bf16(a0, b1, acc[0][1], 0, 0, 0);
    acc[0][2] = __builtin_amdgcn_mfma_f32_16x16x32_bf16(a0, b2, acc[0][2], 0, 0, 0);
    acc[0][3] = __builtin_amdgcn_mfma_f32_16x16x32_bf16(a0, b3, acc[0][3], 0, 0, 0);
    acc[1][0] = __builtin_amdgcn_mfma_f32_16x16x32_bf16(a1, b0, acc[1][0], 0, 0, 0);
    acc[1][1] = __builtin_amdgcn_mfma_f32_16x16x32_bf16(a1, b1, acc[1][1], 0, 0, 0);
    acc[1][2] = __builtin_amdgcn_mfma_f32_16x16x32_bf16(a1, b2, acc[1][2], 0, 0, 0);
    acc[1][3] = __builtin_amdgcn_mfma_f32_16x16x32_bf16(a1, b3, acc[1][3], 0, 0, 0);
  }
#pragma unroll
  for (int ni = 0; ni < 4; ++ni) {
    int col = nBase + wn * 64 + ni * 16 + l15;
    float bcv = bc[col];
#pragma unroll
    for (int mi = 0; mi < 2; ++mi)
#pragma unroll
      for (int r = 0; r < 4; ++r) {
        int row = mBase + wm * 32 + mi * 16 + quad * 4 + r;
        C[(long)row * G4 + col] = (bf16_t)(acc[mi][ni][r] + bcv);
      }
  }
}

// ---------------- hand-rolled two-level grid barrier ----------------
__device__ __forceinline__ void gbar(unsigned* bar, unsigned target) {
  __syncthreads();
  if (threadIdx.x == 0) {
    __builtin_amdgcn_fence(__ATOMIC_RELEASE, "agent");
    unsigned grp = blockIdx.x & (NGRP - 1);
    unsigned o = __hip_atomic_fetch_add(&bar[grp * 32], 1u, __ATOMIC_RELAXED,
                                        __HIP_MEMORY_SCOPE_AGENT);
    if (o == (NBLK / NGRP) - 1) {
      __hip_atomic_store(&bar[grp * 32], 0u, __ATOMIC_RELAXED, __HIP_MEMORY_SCOPE_AGENT);
      unsigned r = __hip_atomic_fetch_add(&bar[512], 1u, __ATOMIC_RELAXED,
                                          __HIP_MEMORY_SCOPE_AGENT);
      if (r == NGRP - 1) {
        __hip_atomic_store(&bar[512], 0u, __ATOMIC_RELAXED, __HIP_MEMORY_SCOPE_AGENT);
        __hip_atomic_store(&bar[544], target, __ATOMIC_RELAXED, __HIP_MEMORY_SCOPE_AGENT);
      }
    }
    while (__hip_atomic_load(&bar[544], __ATOMIC_RELAXED, __HIP_MEMORY_SCOPE_AGENT) != target) {
      __builtin_amdgcn_s_sleep(1);
    }
    __builtin_amdgcn_fence(__ATOMIC_ACQUIRE, "agent");
  }
  __syncthreads();
}

// ---------------- cooperative LSTM recurrence v3 (custom barrier) ----------------
__global__ __launch_bounds__(512) void k_rec3(const bf16_t* __restrict__ gates_x,
                                              const bf16_t* __restrict__ W_hh_bf,
                                              const bf16_t* __restrict__ h0_bf,
                                              bf16_t* __restrict__ h_all,
                                              const float* __restrict__ c0,
                                              unsigned* __restrict__ bar) {
  __shared__ float red[2 * 16 * 16 * 4];  // [cg][b(16)][col(16)][kh(4)] f32

  int bid = blockIdx.x;
  int mi = bid & 1;              // batch half
  int gbase = (bid >> 1) * 8;    // first hidden unit owned by this block
  int tid = threadIdx.x, wid = tid >> 6, lane = tid & 63;
  int cg = wid & 1, kh = wid >> 1;
  int quad = lane >> 4, l15 = lane & 15;

  int wrow = (cg ? 2048 : 0) + ((l15 & 8) ? 1024 : 0) + gbase + (l15 & 7);
  const bf16x8* pw = (const bf16x8*)(W_hh_bf + (long)wrow * NH + kh * 256 + quad * 8);
  bf16x8 wfrag[8];
#pragma unroll
  for (int kk = 0; kk < 8; ++kk) wfrag[kk] = pw[kk * 4];  // resident in VGPRs

  int pb = tid >> 3, pu = tid & 7;
  int u_global = gbase + pu;
  int bglob = mi * 16 + pb;
  float cst = 0.f;
  if (tid < 128) cst = c0[(long)bglob * NH + u_global];

  for (int t = 0; t < T_SEQ - 1; ++t) {
    float gxi = 0.f, gxf = 0.f, gxg = 0.f, gxo = 0.f;
    if (tid < 128) {
      long m = (long)(t * NB + bglob) * G4;
      gxi = (float)gates_x[m + u_global];
      gxf = (float)gates_x[m + 1024 + u_global];
      gxg = (float)gates_x[m + 2048 + u_global];
      gxo = (float)gates_x[m + 3072 + u_global];
    }

    const bf16_t* hp = (t == 0) ? h0_bf : (h_all + (long)(t - 1) * NB * NH);
    const bf16x8* pa = (const bf16x8*)(hp + (long)(mi * 16 + l15) * NH + kh * 256 + quad * 8);
    f32x4 acc = (f32x4){0.f, 0.f, 0.f, 0.f};
#pragma unroll
    for (int kk = 0; kk < 8; ++kk) {
      bf16x8 a = pa[kk * 4];
      acc = __builtin_amdgcn_mfma_f32_16x16x32_bf16(a, wfrag[kk], acc, 0, 0, 0);
    }
#pragma unroll
    for (int r = 0; r < 4; ++r) {
      int b = quad * 4 + r;
      red[(((cg << 4) + b) << 6) + (l15 << 2) + kh] = acc[r];
    }
    __syncthreads();

    if (tid < 128) {
      const float4* rp = (const float4*)red;
      float4 vi = rp[((0 + pb) << 4) + pu];
      float4 vf = rp[((0 + pb) << 4) + 8 + pu];
      float4 vg = rp[((16 + pb) << 4) + pu];
      float4 vo = rp[((16 + pb) << 4) + 8 + pu];
      float iv = vi.x + vi.y + vi.z + vi.w + gxi;
      float fv = vf.x + vf.y + vf.z + vf.w + gxf;
      float gv = vg.x + vg.y + vg.z + vg.w + gxg;
      float ov = vo.x + vo.y + vo.z + vo.w + gxo;
      float si = 1.f / (1.f + __expf(-iv));
      float sf = 1.f / (1.f + __expf(-fv));
      float so = 1.f / (1.f + __expf(-ov));
      float tg = 1.f - 2.f / (__expf(2.f * gv) + 1.f);
      cst = sf * cst + si * tg;
      float th = 1.f - 2.f / (__expf(2.f * cst) + 1.f);
      h_all[(long)(t * NB + bglob) * NH + u_global] = (bf16_t)(so * th);
    }
    gbar(bar, (unsigned)(t + 1));
  }
}

// ---------------- GEMM2 v2: m97-style LDS-staged, exp-rowsum epilogue ----------------
// C(4096x32000) = h_all(4096x1024) @ W_out^T. 128x128 tile, BK=32, 4 waves 2x2,
// each wave 64x64 = 4x4 MFMA 16x16x32. global_load_lds width-16 staging.
__global__ __launch_bounds__(256) void k_gemm2(const bf16_t* __restrict__ A,
                                               const bf16_t* __restrict__ B,
                                               const float* __restrict__ b_out,
                                               float* __restrict__ rowS) {
  __shared__ bf16_t As[128 * 32];
  __shared__ bf16_t Bs[128 * 32];
  const int K = 1024;
  int tid = threadIdx.x, wid = tid >> 6, lane = tid & 63;
  int wm = wid & 1, wn = wid >> 1;
  int quad = lane >> 4, l15 = lane & 15;
  int mBase = blockIdx.x * 128, nBase = blockIdx.y * 128;

  // staging: wave wid stages 16-row chunks {2*wid, 2*wid+1} of A and B.
  // lane: row-in-chunk = lane>>2, 16B segment = lane&3 (row = 32 elems = 64B).
  int rc = lane >> 2, seg = lane & 3;
  int cA0 = 2 * wid, cA1 = 2 * wid + 1;
  const bf16_t* gA0 = A + (size_t)(mBase + cA0 * 16 + rc) * K + seg * 8;
  const bf16_t* gA1 = A + (size_t)(mBase + cA1 * 16 + rc) * K + seg * 8;
  const bf16_t* gB0 = B + (size_t)(nBase + cA0 * 16 + rc) * K + seg * 8;
  const bf16_t* gB1 = B + (size_t)(nBase + cA1 * 16 + rc) * K + seg * 8;
  bf16_t* lA0 = As + cA0 * 512;  // wave-uniform LDS base (16 rows * 32 elems)
  bf16_t* lA1 = As + cA1 * 512;
  bf16_t* lB0 = Bs + cA0 * 512;
  bf16_t* lB1 = Bs + cA1 * 512;

  // fragment read pointers (constant across K-loop)
  const bf16x8* pa[4];
  const bf16x8* pbf[4];
#pragma unroll
  for (int i = 0; i < 4; ++i) {
    pa[i] = (const bf16x8*)(As + (wm * 64 + i * 16 + l15) * 32 + quad * 8);
    pbf[i] = (const bf16x8*)(Bs + (wn * 64 + i * 16 + l15) * 32 + quad * 8);
  }

  f32x4 acc[4][4];
#pragma unroll
  for (int i = 0; i < 4; ++i)
#pragma unroll
    for (int j = 0; j < 4; ++j) acc[i][j] = (f32x4){0.f, 0.f, 0.f, 0.f};

  for (int kt = 0; kt < K / 32; ++kt) {
    g2lds16(gA0 + kt * 32, lA0);
    g2lds16(gA1 + kt * 32, lA1);
    g2lds16(gB0 + kt * 32, lB0);
    g2lds16(gB1 + kt * 32, lB1);
    __syncthreads();  // drains vmcnt (staging complete) + all waves arrived

    bf16x8 af[4], bf[4];
#pragma unroll
    for (int i = 0; i < 4; ++i) { af[i] = *pa[i]; bf[i] = *pbf[i]; }
#pragma unroll
    for (int i = 0; i < 4; ++i)
#pragma unroll
      for (int j = 0; j < 4; ++j)
        acc[i][j] = __builtin_amdgcn_mfma_f32_16x16x32_bf16(af[i], bf[j], acc[i][j], 0, 0, 0);
    __syncthreads();  // LDS reads done before next stage overwrites
  }

  // epilogue: rowS[row] += sum_col exp(acc + b_out[col])
#pragma unroll
  for (int i = 0; i < 4; ++i) {
    float rs[4] = {0.f, 0.f, 0.f, 0.f};
#pragma unroll
    for (int j = 0; j < 4; ++j) {
      int col = nBase + wn * 64 + j * 16 + l15;
      float bb = b_out[col];
#pragma unroll
      for (int r = 0; r < 4; ++r) rs[r] += __expf(acc[i][j][r] + bb);
    }
#pragma unroll
    for (int r = 0; r < 4; ++r) {
#pragma unroll
      for (int s = 1; s < 16; s <<= 1) rs[r] += __shfl_xor(rs[r], s);
      if (l15 == 0) {
        int row = mBase + wm * 64 + i * 16 + quad * 4 + r;
        if (row < MROWS) atomicAdd(&rowS[row], rs[r]);
      }
    }
  }
}

// ---------------- target logits ----------------
__global__ __launch_bounds__(256) void k_tgt(const bf16_t* __restrict__ h_all,
                                             const bf16_t* __restrict__ W_out_bf,
                                             const float* __restrict__ b_out,
                                             const int* __restrict__ tgt,
                                             float* __restrict__ tgt_logit) {
  int gw = (int)((blockIdx.x * blockDim.x + threadIdx.x) >> 6);
  int lane = threadIdx.x & 63;
  if (gw >= MROWS) return;
  int v = tgt[gw];
  const bf16x8* ph = (const bf16x8*)(h_all + (long)gw * NH + lane * 16);
  const bf16x8* pw = (const bf16x8*)(W_out_bf + (long)v * NH + lane * 16);
  float acc = 0.f;
#pragma unroll
  for (int j = 0; j < 2; ++j) {
    bf16x8 h8 = ph[j], w8 = pw[j];
#pragma unroll
    for (int q = 0; q < 8; ++q) acc += (float)h8[q] * (float)w8[q];
  }
#pragma unroll
  for (int s = 1; s < 64; s <<= 1) acc += __shfl_xor(acc, s);
  if (lane == 0) tgt_logit[gw] = acc + b_out[v];
}

// ---------------- final loss reduction ----------------
__global__ __launch_bounds__(256) void k_loss(const float* __restrict__ rowS,
                                              const float* __restrict__ tl,
                                              const int* __restrict__ tgt,
                                              float* __restrict__ out) {
  __shared__ float sm[256];
  float s = 0.f;
  for (int i = threadIdx.x; i < MROWS; i += 256)
    if (tgt[i] != 0) s += logf(rowS[i]) - tl[i];
  sm[threadIdx.x] = s;
  __syncthreads();
  for (int off = 128; off > 0; off >>= 1) {
    if (threadIdx.x < off) sm[threadIdx.x] += sm[threadIdx.x + off];
    __syncthreads();
  }
  if (threadIdx.x == 0) out[0] = sm[0];
}

extern "C" void kernel_launch(void* const* d_in, const int* in_sizes, int n_in,
                              void* d_out, int out_size, void* d_ws, size_t ws_size,
                              hipStream_t stream) {
  const int* idx = (const int*)d_in[0];
  const float* emb = (const float*)d_in[1];
  const float* W_ih = (const float*)d_in[2];
  const float* W_hh = (const float*)d_in[3];
  const float* b_ih = (const float*)d_in[4];
  const float* b_hh = (const float*)d_in[5];
  const float* W_out = (const float*)d_in[6];
  const float* b_out = (const float*)d_in[7];
  const float* h0 = (const float*)d_in[8];
  const float* c0 = (const float*)d_in[9];

  char* ws = (char*)d_ws;
  bf16_t* W_ih_bf = (bf16_t*)ws;            ws += 4096L * 512 * 2;
  bf16_t* W_hh_bf = (bf16_t*)ws;            ws += 4096L * 1024 * 2;
  bf16_t* W_out_bf = (bf16_t*)ws;           ws += 32000L * 1024 * 2;
  bf16_t* x_bf = (bf16_t*)ws;               ws += 4096L * 512 * 2;
  bf16_t* gates_x = (bf16_t*)ws;            ws += 4096L * 4096 * 2;
  bf16_t* h_all = (bf16_t*)ws;              ws += 4096L * 1024 * 2;
  bf16_t* h0_bf = (bf16_t*)ws;              ws += 32L * 1024 * 2;
  float* bc = (float*)ws;                   ws += 4096L * 4;
  float* rowS = (float*)ws;                 ws += 4096L * 4;
  float* tgt_logit = (float*)ws;            ws += 4096L * 4;
  int* tgt = (int*)ws;                      ws += 4096L * 4;
  unsigned* bar = (unsigned*)ws;            ws += 1024L * 4;

  k_prep<<<4096, 256, 0, stream>>>(idx, emb, W_ih, W_hh, b_ih, b_hh, W_out, h0,
                                   W_ih_bf, W_hh_bf, W_out_bf, x_bf, h_all, h0_bf,
                                   bc, rowS, tgt, bar);

  k_gemm1<<<dim3(64, 32), 256, 0, stream>>>(x_bf, W_ih_bf, bc, gates_x);

  {
    void* args[] = {(void*)&gates_x, (void*)&W_hh_bf, (void*)&h0_bf, (void*)&h_all,
                    (void*)&c0, (void*)&bar};
    hipLaunchCooperativeKernel((void*)k_rec3, dim3(NBLK), dim3(512), args, 0, stream);
  }

  k_gemm2<<<dim3(32, 250), 256, 0, stream>>>(h_all, W_out_bf, b_out, rowS);

  k_tgt<<<1016, 256, 0, stream>>>(h_all, W_out_bf, b_out, tgt, tgt_logit);

  k_loss<<<1, 256, 0, stream>>>(rowS, tgt_logit, tgt, (float*)d_out);
}

// Round 5
// 1330.401 us; speedup vs baseline: 4.2744x; 1.5348x over previous
//
#include <hip/hip_runtime.h>
#include <hip/hip_bf16.h>
#include <hip/hip_cooperative_groups.h>
#include <math.h>

namespace cg = cooperative_groups;

typedef __bf16 bf16_t;
typedef bf16_t bf16x8 __attribute__((ext_vector_type(8)));
typedef float f32x4 __attribute__((ext_vector_type(4)));

#define T_SEQ 128
#define NB 32
#define NV 32000
#define NE 512
#define NH 1024
#define G4 4096          // 4*NH
#define MROWS 4064       // 127*32
#define MPAD 4096

#define NBLK 256

// async global->LDS, 16B per lane, wave-uniform LDS base
__device__ __forceinline__ void g2lds16(const bf16_t* g, bf16_t* l) {
  __builtin_amdgcn_global_load_lds((const __attribute__((address_space(1))) void*)g,
                                   (__attribute__((address_space(3))) void*)l, 16, 0, 0);
}

__device__ __forceinline__ unsigned short bf16bits(float x) {
  bf16_t b = (bf16_t)x;
  return __builtin_bit_cast(unsigned short, b);
}

// ---------------- prep: casts, gather, zeroing ----------------
__global__ void k_prep(const int* __restrict__ idx, const float* __restrict__ emb,
                       const float* __restrict__ W_ih, const float* __restrict__ W_hh,
                       const float* __restrict__ b_ih, const float* __restrict__ b_hh,
                       const float* __restrict__ W_out, const float* __restrict__ h0,
                       bf16_t* __restrict__ W_ih_bf, bf16_t* __restrict__ W_hh_bf,
                       bf16_t* __restrict__ W_out_bf, bf16_t* __restrict__ x_bf,
                       bf16_t* __restrict__ h_all, bf16_t* __restrict__ h0_bf,
                       float* __restrict__ bc, float* __restrict__ rowS,
                       int* __restrict__ tgt, unsigned* __restrict__ bar) {
  const long nW_ih = 4096L * 512;
  const long nW_hh = 4096L * 1024;
  const long nW_out = 32000L * 1024;
  const long nX = 4096L * 512;
  const long nH0 = 32L * 1024;
  const long nHpad = 32L * 1024;
  const long NTOTAL = nW_ih + nW_hh + nW_out + nX + nH0 + nHpad + 3 * 4096L + 1024;
  long stride = (long)gridDim.x * blockDim.x;
  for (long i = (long)blockIdx.x * blockDim.x + threadIdx.x; i < NTOTAL; i += stride) {
    long j = i;
    if (j < nW_ih) { W_ih_bf[j] = (bf16_t)W_ih[j]; continue; }
    j -= nW_ih;
    if (j < nW_hh) { W_hh_bf[j] = (bf16_t)W_hh[j]; continue; }
    j -= nW_hh;
    if (j < nW_out) { W_out_bf[j] = (bf16_t)W_out[j]; continue; }
    j -= nW_out;
    if (j < nX) {
      long m = j >> 9; int e = (int)(j & 511);
      float x = 0.f;
      if (m < MROWS) { x = emb[(long)idx[m] * NE + e]; x = x > 0.f ? x : 0.f; }
      x_bf[j] = (bf16_t)x; continue;
    }
    j -= nX;
    if (j < nH0) { h0_bf[j] = (bf16_t)h0[j]; continue; }
    j -= nH0;
    if (j < nHpad) { h_all[4161536L + j] = (bf16_t)0.f; continue; }  // pad rows 4064..4095
    j -= nHpad;
    if (j < 4096) { bc[j] = b_ih[j] + b_hh[j]; continue; }
    j -= 4096;
    if (j < 4096) { rowS[j] = 0.f; continue; }
    j -= 4096;
    if (j < 4096) { tgt[j] = (j < MROWS) ? idx[j + NB] : 0; continue; }
    j -= 4096;
    { bar[j] = 0u; continue; }
  }
}

// ---------------- GEMM1: gates_x = x @ W_ih^T + (b_ih+b_hh), bf16 out ----------------
__global__ __launch_bounds__(256) void k_gemm1(const bf16_t* __restrict__ A,
                                               const bf16_t* __restrict__ B,
                                               const float* __restrict__ bc,
                                               bf16_t* __restrict__ C) {
  const int K = 512;
  int tid = threadIdx.x, wid = tid >> 6, lane = tid & 63;
  int wm = wid & 1, wn = wid >> 1;
  int quad = lane >> 4, l15 = lane & 15;
  int mBase = blockIdx.x * 64, nBase = blockIdx.y * 128;

  const bf16x8* pa0 = (const bf16x8*)(A + (long)(mBase + wm * 32 + l15) * K + quad * 8);
  const bf16x8* pa1 = (const bf16x8*)(A + (long)(mBase + wm * 32 + 16 + l15) * K + quad * 8);
  const bf16x8* pb[4];
#pragma unroll
  for (int j = 0; j < 4; ++j)
    pb[j] = (const bf16x8*)(B + (long)(nBase + wn * 64 + j * 16 + l15) * K + quad * 8);

  f32x4 acc[2][4];
#pragma unroll
  for (int mi = 0; mi < 2; ++mi)
#pragma unroll
    for (int ni = 0; ni < 4; ++ni) acc[mi][ni] = (f32x4){0.f, 0.f, 0.f, 0.f};

  for (int kk = 0; kk < K / 32; ++kk) {
    bf16x8 a0 = pa0[kk * 4], a1 = pa1[kk * 4];
    bf16x8 b0 = pb[0][kk * 4], b1 = pb[1][kk * 4], b2 = pb[2][kk * 4], b3 = pb[3][kk * 4];
    acc[0][0] = __builtin_amdgcn_mfma_f32_16x16x32_bf16(a0, b0, acc[0][0], 0, 0, 0);
    acc[0][1] = __builtin_amdgcn_mfma_f32_16x16x32_bf16(a0, b1, acc[0][1], 0, 0, 0);
    acc[0][2] = __builtin_amdgcn_mfma_f32_16x16x32_bf16(a0, b2, acc[0][2], 0, 0, 0);
    acc[0][3] = __builtin_amdgcn_mfma_f32_16x16x32_bf16(a0, b3, acc[0][3], 0, 0, 0);
    acc[1][0] = __builtin_amdgcn_mfma_f32_16x16x32_bf16(a1, b0, acc[1][0], 0, 0, 0);
    acc[1][1] = __builtin_amdgcn_mfma_f32_16x16x32_bf16(a1, b1, acc[1][1], 0, 0, 0);
    acc[1][2] = __builtin_amdgcn_mfma_f32_16x16x32_bf16(a1, b2, acc[1][2], 0, 0, 0);
    acc[1][3] = __builtin_amdgcn_mfma_f32_16x16x32_bf16(a1, b3, acc[1][3], 0, 0, 0);
  }
#pragma unroll
  for (int ni = 0; ni < 4; ++ni) {
    int col = nBase + wn * 64 + ni * 16 + l15;
    float bcv = bc[col];
#pragma unroll
    for (int mi = 0; mi < 2; ++mi)
#pragma unroll
      for (int r = 0; r < 4; ++r) {
        int row = mBase + wm * 32 + mi * 16 + quad * 4 + r;
        C[(long)row * G4 + col] = (bf16_t)(acc[mi][ni][r] + bcv);
      }
  }
}

// ---------------- fence-free per-half barrier (monotonic counters) ----------------
// All h traffic is write-through coherent (sc0 sc1), so no cache fences needed.
__device__ __forceinline__ void lbar(unsigned* grp, unsigned* root, unsigned* gen,
                                     unsigned target) {
  __syncthreads();
  if (threadIdx.x == 0) {
    asm volatile("" ::: "memory");
    __builtin_amdgcn_s_waitcnt(0x0f70);  // vmcnt(0): my h stores acked at LLC
    unsigned o = __hip_atomic_fetch_add(grp, 1u, __ATOMIC_RELAXED,
                                        __HIP_MEMORY_SCOPE_AGENT);
    if ((o & 15u) == 15u) {
      unsigned r = __hip_atomic_fetch_add(root, 1u, __ATOMIC_RELAXED,
                                          __HIP_MEMORY_SCOPE_AGENT);
      if ((r & 7u) == 7u)
        __hip_atomic_store(gen, (r >> 3) + 1u, __ATOMIC_RELAXED,
                           __HIP_MEMORY_SCOPE_AGENT);
    }
    while (__hip_atomic_load(gen, __ATOMIC_RELAXED, __HIP_MEMORY_SCOPE_AGENT) < target)
      __builtin_amdgcn_s_sleep(1);
    asm volatile("" ::: "memory");
  }
  __syncthreads();
}

// ---------------- LSTM recurrence v4: fence-free coherent h exchange ----------------
// 256 blocks x 512 threads; block = (8 units) x (batch half of 16).
// W_hh fragments VGPR-resident; h stored via agent-scope atomic (sc0 sc1 write-through);
// consumers read fresh addresses with plain vector loads (never cached before).
__global__ __launch_bounds__(512) void k_rec4(const bf16_t* __restrict__ gates_x,
                                              const bf16_t* __restrict__ W_hh_bf,
                                              const bf16_t* __restrict__ h0_bf,
                                              bf16_t* __restrict__ h_all,
                                              const float* __restrict__ c0,
                                              unsigned* __restrict__ bar) {
  __shared__ float red[2 * 16 * 16 * 4];  // [cg][b(16)][col(16)][kh(4)] f32

  int bid = blockIdx.x;
  int mi = bid & 1;              // batch half
  int hb = bid >> 1;             // 0..127 within half
  int gbase = hb * 8;            // first hidden unit owned by this block
  int tid = threadIdx.x, wid = tid >> 6, lane = tid & 63;
  int cg = wid & 1, kh = wid >> 1;
  int quad = lane >> 4, l15 = lane & 15;

  int wrow = (cg ? 2048 : 0) + ((l15 & 8) ? 1024 : 0) + gbase + (l15 & 7);
  const bf16x8* pw = (const bf16x8*)(W_hh_bf + (long)wrow * NH + kh * 256 + quad * 8);
  bf16x8 wfrag[8];
#pragma unroll
  for (int kk = 0; kk < 8; ++kk) wfrag[kk] = pw[kk * 4];  // resident in VGPRs

  // per-half barrier cells (128B-separated lines)
  unsigned* grp = bar + mi * 512 + (hb & 7) * 32;
  unsigned* root = bar + mi * 512 + 256;
  unsigned* gen = bar + mi * 512 + 288;

  // pointwise: threads 0..63 (wave 0): b = tid>>2, unit pair = (tid&3)*2
  int pb = tid >> 2, pu2 = (tid & 3) * 2;
  int u0 = gbase + pu2;
  int bglob = mi * 16 + pb;
  float cst0 = 0.f, cst1 = 0.f;
  if (tid < 64) {
    cst0 = c0[(long)bglob * NH + u0];
    cst1 = c0[(long)bglob * NH + u0 + 1];
  }
  unsigned* h32 = (unsigned*)h_all;

  for (int t = 0; t < T_SEQ - 1; ++t) {
    // prefetch gates_x pairs (independent of h_prev; overlaps barrier wait)
    unsigned gxi2 = 0, gxf2 = 0, gxg2 = 0, gxo2 = 0;
    if (tid < 64) {
      const unsigned* gp = (const unsigned*)(gates_x + (long)(t * NB + bglob) * G4);
      int q = u0 >> 1;
      gxi2 = gp[q]; gxf2 = gp[512 + q]; gxg2 = gp[1024 + q]; gxo2 = gp[1536 + q];
    }

    const bf16_t* hp = (t == 0) ? h0_bf : (h_all + (long)(t - 1) * NB * NH);
    const bf16x8* pa = (const bf16x8*)(hp + (long)(mi * 16 + l15) * NH + kh * 256 + quad * 8);
    f32x4 acc = (f32x4){0.f, 0.f, 0.f, 0.f};
#pragma unroll
    for (int kk = 0; kk < 8; ++kk) {
      bf16x8 a = pa[kk * 4];
      acc = __builtin_amdgcn_mfma_f32_16x16x32_bf16(a, wfrag[kk], acc, 0, 0, 0);
    }
#pragma unroll
    for (int r = 0; r < 4; ++r) {
      int b = quad * 4 + r;
      red[(((cg << 4) + b) << 6) + (l15 << 2) + kh] = acc[r];
    }
    __syncthreads();

    if (tid < 64) {
      const float4* rp = (const float4*)red;
      // two adjacent units d=0,1
      float hv[2];
#pragma unroll
      for (int d = 0; d < 2; ++d) {
        int q = pu2 + d;
        float4 vi = rp[(pb << 4) + q];
        float4 vf = rp[(pb << 4) + 8 + q];
        float4 vg = rp[((16 + pb) << 4) + q];
        float4 vo = rp[((16 + pb) << 4) + 8 + q];
        unsigned bi = d ? (gxi2 & 0xffff0000u) : (gxi2 << 16);
        unsigned bff = d ? (gxf2 & 0xffff0000u) : (gxf2 << 16);
        unsigned bg = d ? (gxg2 & 0xffff0000u) : (gxg2 << 16);
        unsigned bo = d ? (gxo2 & 0xffff0000u) : (gxo2 << 16);
        float iv = vi.x + vi.y + vi.z + vi.w + __builtin_bit_cast(float, bi);
        float fv = vf.x + vf.y + vf.z + vf.w + __builtin_bit_cast(float, bff);
        float gv = vg.x + vg.y + vg.z + vg.w + __builtin_bit_cast(float, bg);
        float ov = vo.x + vo.y + vo.z + vo.w + __builtin_bit_cast(float, bo);
        float si = 1.f / (1.f + __expf(-iv));
        float sf = 1.f / (1.f + __expf(-fv));
        float so = 1.f / (1.f + __expf(-ov));
        float tg = 1.f - 2.f / (__expf(2.f * gv) + 1.f);
        float& cs = d ? cst1 : cst0;
        cs = sf * cs + si * tg;
        float th = 1.f - 2.f / (__expf(2.f * cs) + 1.f);
        hv[d] = so * th;
      }
      unsigned pack = (unsigned)bf16bits(hv[0]) | ((unsigned)bf16bits(hv[1]) << 16);
      // agent-scope write-through store: visible at LLC, no L2 dirty line
      __hip_atomic_store(&h32[(long)(t * NB + bglob) * 512 + (u0 >> 1)], pack,
                         __ATOMIC_RELAXED, __HIP_MEMORY_SCOPE_AGENT);
    }
    if (t < T_SEQ - 2) lbar(grp, root, gen, (unsigned)(t + 1));
  }
}

// ---------------- GEMM2 v2: m97-style LDS-staged, exp-rowsum epilogue ----------------
__global__ __launch_bounds__(256) void k_gemm2(const bf16_t* __restrict__ A,
                                               const bf16_t* __restrict__ B,
                                               const float* __restrict__ b_out,
                                               float* __restrict__ rowS) {
  __shared__ bf16_t As[128 * 32];
  __shared__ bf16_t Bs[128 * 32];
  const int K = 1024;
  int tid = threadIdx.x, wid = tid >> 6, lane = tid & 63;
  int wm = wid & 1, wn = wid >> 1;
  int quad = lane >> 4, l15 = lane & 15;
  int mBase = blockIdx.x * 128, nBase = blockIdx.y * 128;

  int rc = lane >> 2, seg = lane & 3;
  int cA0 = 2 * wid, cA1 = 2 * wid + 1;
  const bf16_t* gA0 = A + (size_t)(mBase + cA0 * 16 + rc) * K + seg * 8;
  const bf16_t* gA1 = A + (size_t)(mBase + cA1 * 16 + rc) * K + seg * 8;
  const bf16_t* gB0 = B + (size_t)(nBase + cA0 * 16 + rc) * K + seg * 8;
  const bf16_t* gB1 = B + (size_t)(nBase + cA1 * 16 + rc) * K + seg * 8;
  bf16_t* lA0 = As + cA0 * 512;
  bf16_t* lA1 = As + cA1 * 512;
  bf16_t* lB0 = Bs + cA0 * 512;
  bf16_t* lB1 = Bs + cA1 * 512;

  const bf16x8* pa[4];
  const bf16x8* pbf[4];
#pragma unroll
  for (int i = 0; i < 4; ++i) {
    pa[i] = (const bf16x8*)(As + (wm * 64 + i * 16 + l15) * 32 + quad * 8);
    pbf[i] = (const bf16x8*)(Bs + (wn * 64 + i * 16 + l15) * 32 + quad * 8);
  }

  f32x4 acc[4][4];
#pragma unroll
  for (int i = 0; i < 4; ++i)
#pragma unroll
    for (int j = 0; j < 4; ++j) acc[i][j] = (f32x4){0.f, 0.f, 0.f, 0.f};

  for (int kt = 0; kt < K / 32; ++kt) {
    g2lds16(gA0 + kt * 32, lA0);
    g2lds16(gA1 + kt * 32, lA1);
    g2lds16(gB0 + kt * 32, lB0);
    g2lds16(gB1 + kt * 32, lB1);
    __syncthreads();

    bf16x8 af[4], bf[4];
#pragma unroll
    for (int i = 0; i < 4; ++i) { af[i] = *pa[i]; bf[i] = *pbf[i]; }
#pragma unroll
    for (int i = 0; i < 4; ++i)
#pragma unroll
      for (int j = 0; j < 4; ++j)
        acc[i][j] = __builtin_amdgcn_mfma_f32_16x16x32_bf16(af[i], bf[j], acc[i][j], 0, 0, 0);
    __syncthreads();
  }

#pragma unroll
  for (int i = 0; i < 4; ++i) {
    float rs[4] = {0.f, 0.f, 0.f, 0.f};
#pragma unroll
    for (int j = 0; j < 4; ++j) {
      int col = nBase + wn * 64 + j * 16 + l15;
      float bb = b_out[col];
#pragma unroll
      for (int r = 0; r < 4; ++r) rs[r] += __expf(acc[i][j][r] + bb);
    }
#pragma unroll
    for (int r = 0; r < 4; ++r) {
#pragma unroll
      for (int s = 1; s < 16; s <<= 1) rs[r] += __shfl_xor(rs[r], s);
      if (l15 == 0) {
        int row = mBase + wm * 64 + i * 16 + quad * 4 + r;
        if (row < MROWS) atomicAdd(&rowS[row], rs[r]);
      }
    }
  }
}

// ---------------- target logits ----------------
__global__ __launch_bounds__(256) void k_tgt(const bf16_t* __restrict__ h_all,
                                             const bf16_t* __restrict__ W_out_bf,
                                             const float* __restrict__ b_out,
                                             const int* __restrict__ tgt,
                                             float* __restrict__ tgt_logit) {
  int gw = (int)((blockIdx.x * blockDim.x + threadIdx.x) >> 6);
  int lane = threadIdx.x & 63;
  if (gw >= MROWS) return;
  int v = tgt[gw];
  const bf16x8* ph = (const bf16x8*)(h_all + (long)gw * NH + lane * 16);
  const bf16x8* pw = (const bf16x8*)(W_out_bf + (long)v * NH + lane * 16);
  float acc = 0.f;
#pragma unroll
  for (int j = 0; j < 2; ++j) {
    bf16x8 h8 = ph[j], w8 = pw[j];
#pragma unroll
    for (int q = 0; q < 8; ++q) acc += (float)h8[q] * (float)w8[q];
  }
#pragma unroll
  for (int s = 1; s < 64; s <<= 1) acc += __shfl_xor(acc, s);
  if (lane == 0) tgt_logit[gw] = acc + b_out[v];
}

// ---------------- final loss reduction ----------------
__global__ __launch_bounds__(256) void k_loss(const float* __restrict__ rowS,
                                              const float* __restrict__ tl,
                                              const int* __restrict__ tgt,
                                              float* __restrict__ out) {
  __shared__ float sm[256];
  float s = 0.f;
  for (int i = threadIdx.x; i < MROWS; i += 256)
    if (tgt[i] != 0) s += logf(rowS[i]) - tl[i];
  sm[threadIdx.x] = s;
  __syncthreads();
  for (int off = 128; off > 0; off >>= 1) {
    if (threadIdx.x < off) sm[threadIdx.x] += sm[threadIdx.x + off];
    __syncthreads();
  }
  if (threadIdx.x == 0) out[0] = sm[0];
}

extern "C" void kernel_launch(void* const* d_in, const int* in_sizes, int n_in,
                              void* d_out, int out_size, void* d_ws, size_t ws_size,
                              hipStream_t stream) {
  const int* idx = (const int*)d_in[0];
  const float* emb = (const float*)d_in[1];
  const float* W_ih = (const float*)d_in[2];
  const float* W_hh = (const float*)d_in[3];
  const float* b_ih = (const float*)d_in[4];
  const float* b_hh = (const float*)d_in[5];
  const float* W_out = (const float*)d_in[6];
  const float* b_out = (const float*)d_in[7];
  const float* h0 = (const float*)d_in[8];
  const float* c0 = (const float*)d_in[9];

  char* ws = (char*)d_ws;
  bf16_t* W_ih_bf = (bf16_t*)ws;            ws += 4096L * 512 * 2;
  bf16_t* W_hh_bf = (bf16_t*)ws;            ws += 4096L * 1024 * 2;
  bf16_t* W_out_bf = (bf16_t*)ws;           ws += 32000L * 1024 * 2;
  bf16_t* x_bf = (bf16_t*)ws;               ws += 4096L * 512 * 2;
  bf16_t* gates_x = (bf16_t*)ws;            ws += 4096L * 4096 * 2;
  bf16_t* h_all = (bf16_t*)ws;              ws += 4096L * 1024 * 2;
  bf16_t* h0_bf = (bf16_t*)ws;              ws += 32L * 1024 * 2;
  float* bc = (float*)ws;                   ws += 4096L * 4;
  float* rowS = (float*)ws;                 ws += 4096L * 4;
  float* tgt_logit = (float*)ws;            ws += 4096L * 4;
  int* tgt = (int*)ws;                      ws += 4096L * 4;
  unsigned* bar = (unsigned*)ws;            ws += 1024L * 4;

  k_prep<<<4096, 256, 0, stream>>>(idx, emb, W_ih, W_hh, b_ih, b_hh, W_out, h0,
                                   W_ih_bf, W_hh_bf, W_out_bf, x_bf, h_all, h0_bf,
                                   bc, rowS, tgt, bar);

  k_gemm1<<<dim3(64, 32), 256, 0, stream>>>(x_bf, W_ih_bf, bc, gates_x);

  {
    void* args[] = {(void*)&gates_x, (void*)&W_hh_bf, (void*)&h0_bf, (void*)&h_all,
                    (void*)&c0, (void*)&bar};
    hipLaunchCooperativeKernel((void*)k_rec4, dim3(NBLK), dim3(512), args, 0, stream);
  }

  k_gemm2<<<dim3(32, 250), 256, 0, stream>>>(h_all, W_out_bf, b_out, rowS);

  k_tgt<<<1016, 256, 0, stream>>>(h_all, W_out_bf, b_out, tgt, tgt_logit);

  k_loss<<<1, 256, 0, stream>>>(rowS, tgt_logit, tgt, (float*)d_out);
}